// Round 1
// baseline (797.353 us; speedup 1.0000x reference)
//
#include <hip/hip_runtime.h>
#include <hip/hip_bf16.h>
#include <math.h>

#define K_ 4
#define B_ 64
#define S_ 50
#define D_ 256
#define V_ 40000
#define H_ 4
#define DH_ 64
#define NEG_ (-1e9f)
#define SCALE_ 0.125f

// ---------- helpers ----------
__device__ __forceinline__ float wred_sum(float v) {
#pragma unroll
  for (int off = 32; off > 0; off >>= 1) v += __shfl_xor(v, off, 64);
  return v;
}
__device__ __forceinline__ float wred_max(float v) {
#pragma unroll
  for (int off = 32; off > 0; off >>= 1) v = fmaxf(v, __shfl_xor(v, off, 64));
  return v;
}
__device__ __forceinline__ float softplusf(float x) {
  return (x > 20.f) ? x : log1pf(expf(x));
}
__device__ __forceinline__ float geluf(float x) {
  const float c = 0.7978845608028654f;  // sqrt(2/pi)
  float x3 = x * x * x;
  return 0.5f * x * (1.f + tanhf(c * (x + 0.044715f * x3)));
}

// ---------- 1. gating ----------
// one wave per (b,s); lane owns 4 consecutive d
__global__ __launch_bounds__(256) void gate_kernel(
    const int* __restrict__ ids, const float* __restrict__ emb,
    const float* __restrict__ Wg, const float* __restrict__ Wn,
    const float* __restrict__ eps, float* __restrict__ gates) {
  int w = threadIdx.x >> 6, lane = threadIdx.x & 63;
  int item = blockIdx.x * 4 + w;  // b*S+s
  int b = item / S_, s = item % S_;
  int d0 = lane * 4;
  float4 hs = make_float4(0.f, 0.f, 0.f, 0.f);
#pragma unroll
  for (int k = 0; k < K_; ++k) {
    int id = ids[(k * B_ + b) * S_ + s];
    const float4 e = *(const float4*)(emb + ((long)k * V_ + id) * D_ + d0);
    hs.x += e.x; hs.y += e.y; hs.z += e.z; hs.w += e.w;
  }
  hs.x *= 0.25f; hs.y *= 0.25f; hs.z *= 0.25f; hs.w *= 0.25f;
  float logit[4];
#pragma unroll
  for (int j = 0; j < K_; ++j) {
    float pg = hs.x * Wg[(d0 + 0) * K_ + j] + hs.y * Wg[(d0 + 1) * K_ + j] +
               hs.z * Wg[(d0 + 2) * K_ + j] + hs.w * Wg[(d0 + 3) * K_ + j];
    float pn = hs.x * Wn[(d0 + 0) * K_ + j] + hs.y * Wn[(d0 + 1) * K_ + j] +
               hs.z * Wn[(d0 + 2) * K_ + j] + hs.w * Wn[(d0 + 3) * K_ + j];
    pg = wred_sum(pg);
    pn = wred_sum(pn);
    logit[j] = pg + softplusf(pn) * eps[item * K_ + j];
  }
  if (lane == 0) {
    int i0 = 0; float v0 = logit[0];
    for (int j = 1; j < K_; ++j) if (logit[j] > v0) { v0 = logit[j]; i0 = j; }
    int i1 = -1; float v1 = 0.f;
    for (int j = 0; j < K_; ++j)
      if (j != i0 && (i1 < 0 || logit[j] > v1)) { v1 = logit[j]; i1 = j; }
    float w0 = 1.f / (1.f + expf(v1 - v0));
    float w1 = 1.f - w0;
#pragma unroll
    for (int j = 0; j < K_; ++j)
      gates[item * K_ + j] = (j == i0) ? w0 : ((j == i1) ? w1 : 0.f);
  }
}

// ---------- 2. local aggregator (graph attention) ----------
// one block per (k,b); wave handles rows i = w, w+4, ...
__global__ __launch_bounds__(256) void local_agg_kernel(
    const int* __restrict__ items, const int* __restrict__ adj,
    const int* __restrict__ alias_, const float* __restrict__ emb,
    const float* __restrict__ agg_a, float* __restrict__ h_out) {
  __shared__ float hg[S_][257];   // stride 257: bank (i+d)%32, conflict-free
  __shared__ float a_s[4][257];
  __shared__ int alias_s[S_];
  int k = blockIdx.x / B_, b = blockIdx.x % B_;
  int t = threadIdx.x;
  for (int f = t; f < S_ * 64; f += 256) {
    int row = f >> 6, c4 = (f & 63) * 4;
    int g = items[(k * B_ + b) * S_ + row];
    const float4 v = *(const float4*)(emb + ((long)k * V_ + g) * D_ + c4);
    hg[row][c4 + 0] = v.x; hg[row][c4 + 1] = v.y;
    hg[row][c4 + 2] = v.z; hg[row][c4 + 3] = v.w;
  }
  {
    int r = t >> 6, c4 = (t & 63) * 4;
    const float4 v = *(const float4*)(agg_a + ((long)k * 4 + r) * D_ + c4);
    a_s[r][c4 + 0] = v.x; a_s[r][c4 + 1] = v.y;
    a_s[r][c4 + 2] = v.z; a_s[r][c4 + 3] = v.w;
  }
  if (t < S_) alias_s[t] = alias_[b * S_ + t];
  __syncthreads();
  int w = t >> 6, lane = t & 63;
  for (int i = w; i < S_; i += 4) {
    int r = 0;
    if (lane < S_) r = adj[((long)b * S_ + i) * S_ + lane];
    int jj = (lane < S_) ? lane : 0;
    int rr = (r > 0) ? (r - 1) : 0;
    float dot = 0.f;
    for (int d = 0; d < D_; ++d)
      dot = fmaf(hg[i][d] * a_s[rr][d], hg[jj][d], dot);
    float val;
    if (lane < S_) val = (r > 0) ? ((dot >= 0.f) ? dot : 0.2f * dot) : NEG_;
    else val = -INFINITY;  // pad lanes contribute 0 even in all-NEG rows
    float m = wred_max(val);
    float p = expf(val - m);
    float ssum = wred_sum(p);
    float alpha = p / ssum;
    float acc0 = 0, acc1 = 0, acc2 = 0, acc3 = 0;
    for (int j = 0; j < S_; ++j) {
      float aj = __shfl(alpha, j, 64);
      acc0 = fmaf(aj, hg[j][lane], acc0);
      acc1 = fmaf(aj, hg[j][lane + 64], acc1);
      acc2 = fmaf(aj, hg[j][lane + 128], acc2);
      acc3 = fmaf(aj, hg[j][lane + 192], acc3);
    }
    for (int s = 0; s < S_; ++s) {
      if (alias_s[s] == i) {  // wave-uniform branch
        float* dst = h_out + (((long)k * B_ + b) * S_ + s) * D_;
        dst[lane] = acc0; dst[lane + 64] = acc1;
        dst[lane + 128] = acc2; dst[lane + 192] = acc3;
      }
    }
  }
}

// ---------- 3. layernorm (one wave per row) ----------
__global__ __launch_bounds__(256) void ln_kernel(
    const float* __restrict__ x, float* __restrict__ y,
    const float* __restrict__ g, const float* __restrict__ bta) {
  int w = threadIdx.x >> 6, lane = threadIdx.x & 63;
  long row = (long)blockIdx.x * 4 + w;  // < K*B*S
  int k = (int)(row / (B_ * S_));
  const float4 v = *(const float4*)(x + row * D_ + lane * 4);
  float sum = wred_sum(v.x + v.y + v.z + v.w);
  float sq = wred_sum(v.x * v.x + v.y * v.y + v.z * v.z + v.w * v.w);
  float mean = sum * (1.f / D_);
  float var = sq * (1.f / D_) - mean * mean;
  float rs = rsqrtf(var + 1e-5f);
  const float4 gv = *(const float4*)(g + k * D_ + lane * 4);
  const float4 bv = *(const float4*)(bta + k * D_ + lane * 4);
  float4 o;
  o.x = (v.x - mean) * rs * gv.x + bv.x;
  o.y = (v.y - mean) * rs * gv.y + bv.y;
  o.z = (v.z - mean) * rs * gv.z + bv.z;
  o.w = (v.w - mean) * rs * gv.w + bv.w;
  *(float4*)(y + row * D_ + lane * 4) = o;
}

// ---------- 4. generic fp32 GEMM: C = act(A@B (+R)) ----------
// 64x64 tile, BK=16, 256 threads, 4x4 microtile. M%64==0, N%64==0, Kd%16==0.
__global__ __launch_bounds__(256) void gemm_kernel(
    const float* __restrict__ A, const float* __restrict__ Bm,
    float* __restrict__ C, const float* __restrict__ R, int M, int N, int Kd,
    long strideA, long strideB, long strideC, long strideR, int act) {
  __shared__ float sA[16][68];  // A tile transposed: sA[kk][row]
  __shared__ float sB[16][68];
  int z = blockIdx.z;
  A += (long)z * strideA;
  Bm += (long)z * strideB;
  C += (long)z * strideC;
  const float* Rp = R ? (R + (long)z * strideR) : (const float*)0;
  int t = threadIdx.x;
  int tx = t & 15, ty = t >> 4;
  int row0 = blockIdx.x * 64, col0 = blockIdx.y * 64;
  int ar = t >> 2, ac = (t & 3) * 4;
  int br = t >> 4, bc = (t & 15) * 4;
  float acc[4][4] = {{0.f}};
  for (int k0 = 0; k0 < Kd; k0 += 16) {
    float4 av = *(const float4*)(A + (long)(row0 + ar) * Kd + k0 + ac);
    float4 bv = *(const float4*)(Bm + (long)(k0 + br) * N + col0 + bc);
    sA[ac + 0][ar] = av.x; sA[ac + 1][ar] = av.y;
    sA[ac + 2][ar] = av.z; sA[ac + 3][ar] = av.w;
    *(float4*)&sB[br][bc] = bv;
    __syncthreads();
#pragma unroll
    for (int kk = 0; kk < 16; ++kk) {
      const float4 a = *(const float4*)&sA[kk][ty * 4];
      const float4 bb = *(const float4*)&sB[kk][tx * 4];
      acc[0][0] = fmaf(a.x, bb.x, acc[0][0]);
      acc[0][1] = fmaf(a.x, bb.y, acc[0][1]);
      acc[0][2] = fmaf(a.x, bb.z, acc[0][2]);
      acc[0][3] = fmaf(a.x, bb.w, acc[0][3]);
      acc[1][0] = fmaf(a.y, bb.x, acc[1][0]);
      acc[1][1] = fmaf(a.y, bb.y, acc[1][1]);
      acc[1][2] = fmaf(a.y, bb.z, acc[1][2]);
      acc[1][3] = fmaf(a.y, bb.w, acc[1][3]);
      acc[2][0] = fmaf(a.z, bb.x, acc[2][0]);
      acc[2][1] = fmaf(a.z, bb.y, acc[2][1]);
      acc[2][2] = fmaf(a.z, bb.z, acc[2][2]);
      acc[2][3] = fmaf(a.z, bb.w, acc[2][3]);
      acc[3][0] = fmaf(a.w, bb.x, acc[3][0]);
      acc[3][1] = fmaf(a.w, bb.y, acc[3][1]);
      acc[3][2] = fmaf(a.w, bb.z, acc[3][2]);
      acc[3][3] = fmaf(a.w, bb.w, acc[3][3]);
    }
    __syncthreads();
  }
#pragma unroll
  for (int i = 0; i < 4; ++i) {
    long row = row0 + ty * 4 + i;
    long off = row * N + col0 + tx * 4;
    float4 o = make_float4(acc[i][0], acc[i][1], acc[i][2], acc[i][3]);
    if (Rp) {
      const float4 rv = *(const float4*)(Rp + off);
      o.x += rv.x; o.y += rv.y; o.z += rv.z; o.w += rv.w;
    }
    if (act == 1) { o.x = geluf(o.x); o.y = geluf(o.y); o.z = geluf(o.z); o.w = geluf(o.w); }
    *(float4*)(C + off) = o;
  }
}

// ---------- 5. causal MHA core: block per (k,b,head) ----------
__global__ __launch_bounds__(256) void attn_kernel(
    const float* __restrict__ q, const float* __restrict__ kx,
    const float* __restrict__ v, float* __restrict__ o) {
  __shared__ float qs[S_][65], ks[S_][65], vs[S_][65];
  int idx = blockIdx.x;
  int h = idx & 3;        // H_=4
  int kb = idx >> 2;      // k*B+b
  long base = ((long)kb * S_) * D_ + h * DH_;
  int t = threadIdx.x;
  for (int f = t; f < S_ * 16; f += 256) {
    int row = f >> 4, c4 = (f & 15) * 4;
    long g = base + (long)row * D_ + c4;
    float4 a = *(const float4*)(q + g);
    qs[row][c4 + 0] = a.x; qs[row][c4 + 1] = a.y;
    qs[row][c4 + 2] = a.z; qs[row][c4 + 3] = a.w;
    float4 bb = *(const float4*)(kx + g);
    ks[row][c4 + 0] = bb.x; ks[row][c4 + 1] = bb.y;
    ks[row][c4 + 2] = bb.z; ks[row][c4 + 3] = bb.w;
    float4 c = *(const float4*)(v + g);
    vs[row][c4 + 0] = c.x; vs[row][c4 + 1] = c.y;
    vs[row][c4 + 2] = c.z; vs[row][c4 + 3] = c.w;
  }
  __syncthreads();
  int w = t >> 6, lane = t & 63;
  for (int i = w; i < S_; i += 4) {
    int jj = (lane < S_) ? lane : 0;
    float dot = 0.f;
#pragma unroll
    for (int d = 0; d < DH_; ++d) dot = fmaf(qs[i][d], ks[jj][d], dot);
    float val = (lane <= i) ? dot * SCALE_ : ((lane < S_) ? NEG_ : -INFINITY);
    float m = wred_max(val);
    float p = expf(val - m);
    float ssum = wred_sum(p);
    float pr = p / ssum;
    float acc = 0.f;
    for (int j = 0; j <= i; ++j)
      acc = fmaf(__shfl(pr, j, 64), vs[j][lane], acc);
    o[base + (long)i * D_ + lane] = acc;
  }
}

// ---------- 6. gated combine ----------
__global__ __launch_bounds__(256) void combine_kernel(
    const float* __restrict__ gates, const float* __restrict__ h,
    float* __restrict__ out) {
  int w = threadIdx.x >> 6, lane = threadIdx.x & 63;
  int item = blockIdx.x * 4 + w;  // b*S+s
  float g0 = gates[item * 4 + 0], g1 = gates[item * 4 + 1];
  float g2 = gates[item * 4 + 2], g3 = gates[item * 4 + 3];
  long off = (long)item * D_ + lane * 4;
  const long PK = (long)B_ * S_ * D_;  // 819200
  float4 a = *(const float4*)(h + off);
  float4 b = *(const float4*)(h + PK + off);
  float4 c = *(const float4*)(h + 2 * PK + off);
  float4 d = *(const float4*)(h + 3 * PK + off);
  float4 o;
  o.x = g0 * a.x + g1 * b.x + g2 * c.x + g3 * d.x;
  o.y = g0 * a.y + g1 * b.y + g2 * c.y + g3 * d.y;
  o.z = g0 * a.z + g1 * b.z + g2 * c.z + g3 * d.z;
  o.w = g0 * a.w + g1 * b.w + g2 * c.w + g3 * d.w;
  *(float4*)(out + off) = o;
}

extern "C" void kernel_launch(void* const* d_in, const int* in_sizes, int n_in,
                              void* d_out, int out_size, void* d_ws,
                              size_t ws_size, hipStream_t stream) {
  const int* ids = (const int*)d_in[0];
  const int* items = (const int*)d_in[1];
  const int* adj = (const int*)d_in[2];
  const int* alias = (const int*)d_in[3];
  const float* eps = (const float*)d_in[4];
  const float* emb = (const float*)d_in[5];
  const float* agg_a = (const float*)d_in[6];
  const float* Wq = (const float*)d_in[7];
  const float* Wk = (const float*)d_in[8];
  const float* Wv = (const float*)d_in[9];
  const float* Wo = (const float*)d_in[10];
  const float* ln1g = (const float*)d_in[11];
  const float* ln1b = (const float*)d_in[12];
  const float* W1 = (const float*)d_in[13];
  const float* W2 = (const float*)d_in[14];
  const float* ln2g = (const float*)d_in[15];
  const float* ln2b = (const float*)d_in[16];
  const float* Wg = (const float*)d_in[17];
  const float* Wn = (const float*)d_in[18];
  float* out = (float*)d_out;

  const long BSD = (long)B_ * S_ * D_;        // 819200 per-key stride
  const size_t BIG = (size_t)K_ * B_ * S_ * D_;  // 3276800 full buffer
  float* ws = (float*)d_ws;
  float* gates = ws;                 // 16384 (12800 used)
  float* hbuf = ws + 16384;          // [K,B,S,D] residual stream
  float* xbuf = hbuf + BIG;          // LN1 out; later reused as attention O
  float* qbuf = xbuf + BIG;          // Q; later reused as LN2 out (y)
  float* kbuf = qbuf + BIG;          // Kproj
  float* vbuf = kbuf + BIG;          // Vproj; fallback FFN hidden
  float* tbuf = vbuf + BIG;          // FFN hidden [K,B,S,4D] (full path)
  bool full = ws_size >= (size_t)(16384 + 5 * 3276800 + 13107200) * 4;

  gate_kernel<<<800, 256, 0, stream>>>(ids, emb, Wg, Wn, eps, gates);
  local_agg_kernel<<<K_ * B_, 256, 0, stream>>>(items, adj, alias, emb, agg_a, hbuf);
  ln_kernel<<<3200, 256, 0, stream>>>(hbuf, xbuf, ln1g, ln1b);
  const long DD = (long)D_ * D_;      // 65536
  const long DH4 = (long)D_ * 4 * D_; // 262144
  gemm_kernel<<<dim3(50, 4, 4), 256, 0, stream>>>(xbuf, Wq, qbuf, (const float*)0,
      3200, 256, 256, BSD, DD, BSD, 0, 0);
  gemm_kernel<<<dim3(50, 4, 4), 256, 0, stream>>>(xbuf, Wk, kbuf, (const float*)0,
      3200, 256, 256, BSD, DD, BSD, 0, 0);
  gemm_kernel<<<dim3(50, 4, 4), 256, 0, stream>>>(xbuf, Wv, vbuf, (const float*)0,
      3200, 256, 256, BSD, DD, BSD, 0, 0);
  attn_kernel<<<K_ * B_ * H_, 256, 0, stream>>>(qbuf, kbuf, vbuf, xbuf);
  gemm_kernel<<<dim3(50, 4, 4), 256, 0, stream>>>(xbuf, Wo, hbuf, hbuf,
      3200, 256, 256, BSD, DD, BSD, BSD, 0);
  ln_kernel<<<3200, 256, 0, stream>>>(hbuf, qbuf, ln2g, ln2b);
  if (full) {
    gemm_kernel<<<dim3(50, 16, 4), 256, 0, stream>>>(qbuf, W1, tbuf, (const float*)0,
        3200, 1024, 256, BSD, DH4, (long)B_ * S_ * 4 * D_, 0, 1);
    gemm_kernel<<<dim3(50, 4, 4), 256, 0, stream>>>(tbuf, W2, hbuf, hbuf,
        3200, 256, 1024, (long)B_ * S_ * 4 * D_, DH4, BSD, BSD, 0);
  } else {
    for (int k = 0; k < K_; ++k) {
      gemm_kernel<<<dim3(50, 16, 1), 256, 0, stream>>>(qbuf + k * BSD, W1 + (long)k * DH4,
          vbuf, (const float*)0, 3200, 1024, 256, 0, 0, 0, 0, 1);
      gemm_kernel<<<dim3(50, 4, 1), 256, 0, stream>>>(vbuf, W2 + (long)k * DH4,
          hbuf + k * BSD, hbuf + k * BSD, 3200, 256, 1024, 0, 0, 0, 0, 0);
    }
  }
  combine_kernel<<<800, 256, 0, stream>>>(gates, hbuf, out);
}